// Round 6
// baseline (105.130 us; speedup 1.0000x reference)
//
#include <hip/hip_runtime.h>
#include <hip/hip_bf16.h>
#include <math.h>

#define DFEAT 128
#define KNBR  16
#define NPB   64   // nodes per block

typedef __attribute__((ext_vector_type(8))) short short8;
typedef __attribute__((ext_vector_type(4))) float f32x4;

__device__ __forceinline__ unsigned short f2bf(float x) {
    union { float f; unsigned u; } v; v.f = x;
    unsigned r = v.u + 0x7FFFu + ((v.u >> 16) & 1u);   // round-nearest-even
    return (unsigned short)(r >> 16);
}
__device__ __forceinline__ float bf2f(unsigned short u) {
    union { unsigned u; float f; } v; v.u = ((unsigned)u) << 16; return v.f;
}

// ---- fused prep: wcat (first 4096 threads) + h16 (rest), 8 elems/thread ----
__global__ __launch_bounds__(256)
void prep_kernel(const float* __restrict__ h,
                 const float* __restrict__ wself,
                 const float* __restrict__ wnei,
                 unsigned short* __restrict__ h16,
                 unsigned short* __restrict__ wcat,
                 int ntot8) {
    const int t = blockIdx.x * 256 + threadIdx.x;
    if (t < 4096) {
        const int base = t * 8;
        const int j = base >> 8;
        const int d0 = base & 255;
        const float* src = (d0 < DFEAT) ? (wself + j * DFEAT + d0)
                                        : (wnei  + j * DFEAT + (d0 - DFEAT));
        f32x4 a = ((const f32x4*)src)[0], b = ((const f32x4*)src)[1];
        short8 o;
        o[0] = f2bf(a[0]); o[1] = f2bf(a[1]); o[2] = f2bf(a[2]); o[3] = f2bf(a[3]);
        o[4] = f2bf(b[0]); o[5] = f2bf(b[1]); o[6] = f2bf(b[2]); o[7] = f2bf(b[3]);
        *(short8*)(wcat + base) = o;
        return;
    }
    const long u = (long)t - 4096;
    if (u >= ntot8) return;
    f32x4 a = __builtin_nontemporal_load((const f32x4*)(h + u * 8));
    f32x4 b = __builtin_nontemporal_load((const f32x4*)(h + u * 8) + 1);
    short8 o;
    o[0] = f2bf(a[0]); o[1] = f2bf(a[1]); o[2] = f2bf(a[2]); o[3] = f2bf(a[3]);
    o[4] = f2bf(b[0]); o[5] = f2bf(b[1]); o[6] = f2bf(b[2]); o[7] = f2bf(b[3]);
    __builtin_nontemporal_store(o, (short8*)(h16 + u * 8));
}

template<int H16>
__global__ __launch_bounds__(256, 4)
void sage_fused_kernel(const float* __restrict__ h,
                       const unsigned short* __restrict__ h16,
                       const int* __restrict__ nbr32,
                       const float* __restrict__ nbrw,
                       const unsigned short* __restrict__ wcat,
                       const float* __restrict__ gamma,
                       const float* __restrict__ beta,
                       float* __restrict__ out,
                       int N) {
    // x tile: 64 nodes x 256 k, bf16, XOR-swizzled on 16B chunks (c ^= row&7)
    // LN scratch is OVERLAID on xlds (dead after the MFMA loop) -> 32 KB total
    __shared__ __align__(16) unsigned short xlds[NPB][256];   // 32 KB exactly

    const int tid = threadIdx.x;
    const int nb  = blockIdx.x * NPB;

    // int64-vs-int32 index dtype detection (idx < 2^17 => int64 odd words all 0)
    const bool idx64 = ((nbr32[1] | nbr32[3] | nbr32[5] | nbr32[7] |
                         nbr32[9] | nbr32[11] | nbr32[13] | nbr32[15]) == 0);

    const int l   = tid & 63;
    const int wvi = tid >> 6;     // wave 0..3
    const int q   = l & 15;       // lane-in-group: dims [q*8, q*8+8)
    const int gb  = l & 48;       // group base lane within wave
    const int i0  = wvi * 16 + (l >> 4) * 4;   // first node-in-tile of this group

    // ---------------- Phase 1: gather + stage (asm-forced 16-deep pipeline) ----
    if constexpr (H16) {
        int myidx[4]; float myw[4]; int nn[4];
        #pragma unroll
        for (int r = 0; r < 4; ++r) {
            int n = nb + i0 + r; if (n >= N) n = N - 1;
            nn[r] = n;
            const int e = n * KNBR + q;
            myidx[r] = nbr32[idx64 ? 2 * e : e];
            myw[r]   = nbrw[e];
        }
        // stage self rows to LDS now (frees regs; drains those loads)
        #pragma unroll
        for (int r = 0; r < 4; ++r) {
            const int i = i0 + r;
            short8 hvv = *(const short8*)(h16 + (long)nn[r] * DFEAT + q * 8);
            *(short8*)&xlds[i][(q ^ (i & 7)) * 8] = hvv;
        }
        // force compiler-tracked loads (idx/w) to be waited HERE, so no
        // compiler vmcnt lands inside the asm region
        asm volatile("" :: "v"(myidx[0]), "v"(myidx[1]), "v"(myidx[2]), "v"(myidx[3]),
                           "v"(myw[0]), "v"(myw[1]), "v"(myw[2]), "v"(myw[3]));
        asm volatile("s_waitcnt vmcnt(0)" ::: "memory");
        __builtin_amdgcn_sched_barrier(0);

        short8 a0, a1, a2, a3, a4, a5, a6, a7;   // half A: k=0..7
        short8 b0, b1, b2, b3, b4, b5, b6, b7;   // half B: k=8..15
        float acc[8];

        #define LD(dst, r, kk)                                                   \
            asm volatile("global_load_dwordx4 %0, %1, off"                       \
                : "=v"(dst)                                                      \
                : "v"((const short8*)(h16 +                                      \
                      (long)(unsigned)__shfl(myidx[r], gb + (kk), 64) * DFEAT +  \
                      q * 8)))
        #define ISSUE_A(r) { LD(a0,r,0); LD(a1,r,1); LD(a2,r,2); LD(a3,r,3);     \
                             LD(a4,r,4); LD(a5,r,5); LD(a6,r,6); LD(a7,r,7); }
        #define ISSUE_B(r) { LD(b0,r,8); LD(b1,r,9); LD(b2,r,10); LD(b3,r,11);   \
                             LD(b4,r,12); LD(b5,r,13); LD(b6,r,14); LD(b7,r,15); }
        #define WAITV8 { asm volatile("s_waitcnt vmcnt(8)" ::: "memory");        \
                         __builtin_amdgcn_sched_barrier(0); }
        #define WAITV0 { asm volatile("s_waitcnt vmcnt(0)" ::: "memory");        \
                         __builtin_amdgcn_sched_barrier(0); }
        #define CONS1(BUF, r, kk) {                                              \
            float wk = __shfl(myw[r], gb + (kk), 64);                            \
            _Pragma("unroll")                                                    \
            for (int d = 0; d < 8; ++d)                                          \
                acc[d] += wk * bf2f((unsigned short)BUF[d]); }
        #define CONSUME_A(r) { CONS1(a0,r,0) CONS1(a1,r,1) CONS1(a2,r,2)         \
                               CONS1(a3,r,3) CONS1(a4,r,4) CONS1(a5,r,5)         \
                               CONS1(a6,r,6) CONS1(a7,r,7) }
        #define CONSUME_B(r) { CONS1(b0,r,8) CONS1(b1,r,9) CONS1(b2,r,10)        \
                               CONS1(b3,r,11) CONS1(b4,r,12) CONS1(b5,r,13)      \
                               CONS1(b6,r,14) CONS1(b7,r,15) }
        #define RESET() { _Pragma("unroll") for (int d = 0; d < 8; ++d) acc[d] = 0.f; }
        #define STOREAGG(r) {                                                    \
            const int i = i0 + (r);                                              \
            short8 ab;                                                           \
            _Pragma("unroll") for (int d = 0; d < 8; ++d) ab[d] = f2bf(acc[d]);  \
            *(short8*)&xlds[i][((16 + q) ^ (i & 7)) * 8] = ab; }

        ISSUE_A(0); ISSUE_B(0);                       // 16 in flight
        RESET(); WAITV8; CONSUME_A(0); ISSUE_A(1);
                 WAITV8; CONSUME_B(0); ISSUE_B(1); STOREAGG(0);
        RESET(); WAITV8; CONSUME_A(1); ISSUE_A(2);
                 WAITV8; CONSUME_B(1); ISSUE_B(2); STOREAGG(1);
        RESET(); WAITV8; CONSUME_A(2); ISSUE_A(3);
                 WAITV8; CONSUME_B(2); ISSUE_B(3); STOREAGG(2);
        RESET(); WAITV8; CONSUME_A(3);
                 WAITV0; CONSUME_B(3); STOREAGG(3);

        #undef LD
        #undef ISSUE_A
        #undef ISSUE_B
        #undef WAITV8
        #undef WAITV0
        #undef CONS1
        #undef CONSUME_A
        #undef CONSUME_B
        #undef RESET
        #undef STOREAGG
    } else {
        #pragma unroll 1
        for (int r = 0; r < 4; ++r) {
            const int i = i0 + r;
            int n = nb + i; if (n >= N) n = N - 1;
            short8 hv;
            float acc[8] = {0.f,0.f,0.f,0.f,0.f,0.f,0.f,0.f};
            const f32x4* hrow = (const f32x4*)(h + (long)n * DFEAT + q * 8);
            f32x4 h0 = hrow[0], h1 = hrow[1];
            hv[0] = f2bf(h0[0]); hv[1] = f2bf(h0[1]); hv[2] = f2bf(h0[2]); hv[3] = f2bf(h0[3]);
            hv[4] = f2bf(h1[0]); hv[5] = f2bf(h1[1]); hv[6] = f2bf(h1[2]); hv[7] = f2bf(h1[3]);
            const int e0 = n * KNBR;
            #pragma unroll 4
            for (int k = 0; k < KNBR; ++k) {
                float w = nbrw[e0 + k];
                int idx = nbr32[idx64 ? 2 * (e0 + k) : (e0 + k)];
                const f32x4* nrow = (const f32x4*)(h + (long)idx * DFEAT + q * 8);
                f32x4 n0 = nrow[0], n1 = nrow[1];
                acc[0] += w * n0[0]; acc[1] += w * n0[1];
                acc[2] += w * n0[2]; acc[3] += w * n0[3];
                acc[4] += w * n1[0]; acc[5] += w * n1[1];
                acc[6] += w * n1[2]; acc[7] += w * n1[3];
            }
            *(short8*)&xlds[i][(q ^ (i & 7)) * 8] = hv;
            short8 ab;
            #pragma unroll
            for (int d = 0; d < 8; ++d) ab[d] = f2bf(acc[d]);
            *(short8*)&xlds[i][((16 + q) ^ (i & 7)) * 8] = ab;
        }
    }
    __syncthreads();

    // ---------------- Phase 2: MFMA GEMM (64 nodes x 128 j, K=256) ----------------
    const int wv  = wvi;          // wave owns j in [wv*32, wv*32+32)
    const int col = l & 15;
    const int kg  = l >> 4;       // 0..3

    f32x4 acc2[4][2];
    #pragma unroll
    for (int s = 0; s < 4; ++s)
        #pragma unroll
        for (int t = 0; t < 2; ++t)
            acc2[s][t] = (f32x4){0.f, 0.f, 0.f, 0.f};

    const unsigned short* wbase0 = wcat + (wv * 32 + col) * 256 + kg * 8;
    const unsigned short* wbase1 = wbase0 + 16 * 256;

    #pragma unroll
    for (int kk = 0; kk < 8; ++kk) {
        short8 b0 = *(const short8*)(wbase0 + kk * 32);   // B[k][col] = Wcat[j][k]
        short8 b1 = *(const short8*)(wbase1 + kk * 32);
        #pragma unroll
        for (int s = 0; s < 4; ++s) {
            const int row = s * 16 + col;                  // A row = node in tile
            const int c = (kk * 4 + kg) ^ (row & 7);       // swizzled 16B chunk
            short8 a = *(const short8*)&xlds[row][c * 8];
            acc2[s][0] = __builtin_amdgcn_mfma_f32_16x16x32_bf16(a, b0, acc2[s][0], 0, 0, 0);
            acc2[s][1] = __builtin_amdgcn_mfma_f32_16x16x32_bf16(a, b1, acc2[s][1], 0, 0, 0);
        }
    }

    // ---------------- Phase 3: GELU (exact erf) ----------------
    float y[4][2][4];
    #pragma unroll
    for (int s = 0; s < 4; ++s)
        #pragma unroll
        for (int t = 0; t < 2; ++t)
            #pragma unroll
            for (int r = 0; r < 4; ++r) {
                float x = acc2[s][t][r];
                y[s][t][r] = 0.5f * x * (1.0f + erff(x * 0.70710678118654752f));
            }

    __syncthreads();   // all xlds reads done before LN-scratch overlay writes

    // overlay LN scratch on the dead x tile
    float* lsum = (float*)&xlds[0][0];        // [4][64]
    float* lsq  = lsum + 4 * NPB;             // [4][64]

    // ---------------- Phase 4: LN stats ----------------
    #pragma unroll
    for (int s = 0; s < 4; ++s) {
        f32x4 sm, sq;
        #pragma unroll
        for (int r = 0; r < 4; ++r) {
            float a0 = y[s][0][r], a1 = y[s][1][r];
            sm[r] = a0 + a1;
            sq[r] = a0 * a0 + a1 * a1;
        }
        #pragma unroll
        for (int m = 1; m < 16; m <<= 1) {
            #pragma unroll
            for (int r = 0; r < 4; ++r) {
                sm[r] += __shfl_xor(sm[r], m, 64);
                sq[r] += __shfl_xor(sq[r], m, 64);
            }
        }
        if (col == 0) {
            *(f32x4*)&lsum[wv * NPB + s * 16 + kg * 4] = sm;
            *(f32x4*)&lsq [wv * NPB + s * 16 + kg * 4] = sq;
        }
    }
    __syncthreads();

    // ---------------- Phase 5: LN apply + store (non-temporal) ----------------
    const float g0  = gamma[wv * 32 + col];
    const float g1  = gamma[wv * 32 + 16 + col];
    const float be0 = beta [wv * 32 + col];
    const float be1 = beta [wv * 32 + 16 + col];

    #pragma unroll
    for (int s = 0; s < 4; ++s) {
        f32x4 sm = {0.f,0.f,0.f,0.f}, sq = {0.f,0.f,0.f,0.f};
        #pragma unroll
        for (int u = 0; u < 4; ++u) {
            f32x4 a = *(const f32x4*)&lsum[u * NPB + s * 16 + kg * 4];
            f32x4 b = *(const f32x4*)&lsq [u * NPB + s * 16 + kg * 4];
            sm += a; sq += b;
        }
        #pragma unroll
        for (int r = 0; r < 4; ++r) {
            const int i = s * 16 + kg * 4 + r;
            const int n = nb + i;
            if (n < N) {
                float mean = sm[r] * (1.0f / 128.0f);
                float var  = sq[r] * (1.0f / 128.0f) - mean * mean;
                float rstd = rsqrtf(var + 1e-5f);
                long o = (long)n * DFEAT + wv * 32 + col;
                __builtin_nontemporal_store((y[s][0][r] - mean) * rstd * g0 + be0, &out[o]);
                __builtin_nontemporal_store((y[s][1][r] - mean) * rstd * g1 + be1, &out[o + 16]);
            }
        }
    }
}

extern "C" void kernel_launch(void* const* d_in, const int* in_sizes, int n_in,
                              void* d_out, int out_size, void* d_ws, size_t ws_size,
                              hipStream_t stream) {
    const float* h     = (const float*)d_in[0];
    const int*   nbr   = (const int*)  d_in[1];
    const float* nbrw  = (const float*)d_in[2];
    const float* wself = (const float*)d_in[3];
    const float* wnei  = (const float*)d_in[4];
    const float* gamma = (const float*)d_in[5];
    const float* beta  = (const float*)d_in[6];
    const int N = in_sizes[0] / DFEAT;

    unsigned short* wcat = (unsigned short*)d_ws;               // 64 KB
    unsigned short* h16  = (unsigned short*)((char*)d_ws + 65536);
    const size_t need = 65536 + (size_t)N * DFEAT * sizeof(unsigned short);

    const int blocks = (N + NPB - 1) / NPB;
    if (ws_size >= need) {
        const int ntot8 = N * DFEAT / 8;
        const int pthreads = 4096 + ntot8;
        prep_kernel<<<(pthreads + 255) / 256, 256, 0, stream>>>(h, wself, wnei, h16, wcat, ntot8);
        sage_fused_kernel<1><<<blocks, 256, 0, stream>>>(h, h16, nbr, nbrw, wcat,
                                                         gamma, beta, (float*)d_out, N);
    } else {
        prep_kernel<<<(4096 + 255) / 256, 256, 0, stream>>>(h, wself, wnei, h16, wcat, 0);
        sage_fused_kernel<0><<<blocks, 256, 0, stream>>>(h, (const unsigned short*)nullptr,
                                                         nbr, nbrw, wcat,
                                                         gamma, beta, (float*)d_out, N);
    }
}

// Round 8
// 85.863 us; speedup vs baseline: 1.2244x; 1.2244x over previous
//
#include <hip/hip_runtime.h>
#include <hip/hip_bf16.h>
#include <math.h>

#define DFEAT 128
#define KNBR  16
#define NPB   64   // nodes per block

typedef __attribute__((ext_vector_type(8))) short short8;
typedef __attribute__((ext_vector_type(4))) float f32x4;
typedef __attribute__((ext_vector_type(2))) unsigned u32x2;
typedef __attribute__((ext_vector_type(4))) unsigned u32x4;

__device__ __forceinline__ unsigned short f2bf(float x) {
    union { float f; unsigned u; } v; v.f = x;
    unsigned r = v.u + 0x7FFFu + ((v.u >> 16) & 1u);   // round-nearest-even
    return (unsigned short)(r >> 16);
}
__device__ __forceinline__ float bf2f(unsigned short u) {
    union { unsigned u; float f; } v; v.u = ((unsigned)u) << 16; return v.f;
}

// ---- fused prep: wcat (first 4096 threads) + h16 / int8-row-scaled h8i (rest) ----
// h-thread u: row = u>>4, part = u&15, dims [part*8, part*8+8)
__global__ __launch_bounds__(256)
void prep_kernel(const float* __restrict__ h,
                 const float* __restrict__ wself,
                 const float* __restrict__ wnei,
                 unsigned short* __restrict__ h16,
                 unsigned short* __restrict__ wcat,
                 unsigned char* __restrict__ h8i,
                 float* __restrict__ sc,
                 int ntot8) {
    const int t = blockIdx.x * 256 + threadIdx.x;
    if (t < 4096) {
        const int base = t * 8;
        const int j = base >> 8;
        const int d0 = base & 255;
        const float* src = (d0 < DFEAT) ? (wself + j * DFEAT + d0)
                                        : (wnei  + j * DFEAT + (d0 - DFEAT));
        f32x4 a = ((const f32x4*)src)[0], b = ((const f32x4*)src)[1];
        short8 o;
        o[0] = f2bf(a[0]); o[1] = f2bf(a[1]); o[2] = f2bf(a[2]); o[3] = f2bf(a[3]);
        o[4] = f2bf(b[0]); o[5] = f2bf(b[1]); o[6] = f2bf(b[2]); o[7] = f2bf(b[3]);
        *(short8*)(wcat + base) = o;
        return;
    }
    const long u = (long)t - 4096;
    if (u >= ntot8) return;
    f32x4 a = __builtin_nontemporal_load((const f32x4*)(h + u * 8));
    f32x4 b = __builtin_nontemporal_load((const f32x4*)(h + u * 8) + 1);
    short8 o;
    o[0] = f2bf(a[0]); o[1] = f2bf(a[1]); o[2] = f2bf(a[2]); o[3] = f2bf(a[3]);
    o[4] = f2bf(b[0]); o[5] = f2bf(b[1]); o[6] = f2bf(b[2]); o[7] = f2bf(b[3]);
    __builtin_nontemporal_store(o, (short8*)(h16 + u * 8));

    if (h8i) {
        // per-row max over the 16-lane subgroup (u contiguous, 16-aligned per wave)
        float m = 0.f;
        #pragma unroll
        for (int d = 0; d < 4; ++d) { m = fmaxf(m, fabsf(a[d])); m = fmaxf(m, fabsf(b[d])); }
        #pragma unroll
        for (int mk = 1; mk < 16; mk <<= 1) m = fmaxf(m, __shfl_xor(m, mk, 64));
        const float inv = (m > 0.f) ? 127.f / m : 0.f;
        u32x2 q;
        q[0] = ((unsigned)((int)rintf(a[0] * inv) & 255))
             | ((unsigned)((int)rintf(a[1] * inv) & 255) << 8)
             | ((unsigned)((int)rintf(a[2] * inv) & 255) << 16)
             | ((unsigned)((int)rintf(a[3] * inv) & 255) << 24);
        q[1] = ((unsigned)((int)rintf(b[0] * inv) & 255))
             | ((unsigned)((int)rintf(b[1] * inv) & 255) << 8)
             | ((unsigned)((int)rintf(b[2] * inv) & 255) << 16)
             | ((unsigned)((int)rintf(b[3] * inv) & 255) << 24);
        __builtin_nontemporal_store(q, (u32x2*)(h8i + u * 8));
        if ((u & 15) == 0) sc[u >> 4] = m * (1.f / 127.f);
    }
}

// MODE: 0 = f32 direct, 1 = bf16 table, 3 = int8+row-scale gather, bf16 self
template<int MODE>
__global__ __launch_bounds__(256, 4)
void sage_fused_kernel(const float* __restrict__ h,
                       const unsigned short* __restrict__ h16,
                       const unsigned char* __restrict__ h8i,
                       const float* __restrict__ sc,
                       const int* __restrict__ nbr32,
                       const float* __restrict__ nbrw,
                       const unsigned short* __restrict__ wcat,
                       const float* __restrict__ gamma,
                       const float* __restrict__ beta,
                       float* __restrict__ out,
                       int N) {
    // x tile: 64 nodes x 256 k, bf16, XOR-swizzled on 16B chunks (c ^= row&7)
    // LN scratch is OVERLAID on xlds (dead after the MFMA loop) -> 32 KB total
    __shared__ __align__(16) unsigned short xlds[NPB][256];   // 32 KB exactly

    const int tid = threadIdx.x;
    const int nb  = blockIdx.x * NPB;

    // int64-vs-int32 index dtype detection (idx < 2^17 => int64 odd words all 0)
    const bool idx64 = ((nbr32[1] | nbr32[3] | nbr32[5] | nbr32[7] |
                         nbr32[9] | nbr32[11] | nbr32[13] | nbr32[15]) == 0);

    const int l   = tid & 63;
    const int wvi = tid >> 6;     // wave 0..3

    // ---------------- Phase 1: gather + stage ----------------
    if constexpr (MODE == 3) {
        const int q8  = l & 7;          // lane-in-group: dims [q8*16, q8*16+16)
        const int gb2 = l & 56;         // 8-lane group base within wave
        const int i0b = wvi * 16 + (l >> 3) * 2;   // group's first node-in-tile

        #pragma unroll
        for (int r = 0; r < 2; ++r) {
            const int i = i0b + r;
            int n = nb + i; if (n >= N) n = N - 1;

            // lane owns edges q8 and q8+8 of node n; fold row-scale into weight
            const int e0 = n * KNBR + q8;
            const int id0 = nbr32[idx64 ? 2 * e0 : e0];
            const int id1 = nbr32[idx64 ? 2 * (e0 + 8) : (e0 + 8)];
            const float w0 = nbrw[e0]     * sc[id0];
            const float w1 = nbrw[e0 + 8] * sc[id1];

            // self row (bf16 table): dims [q8*16, q8*16+16) = chunks 2q8, 2q8+1
            short8 hv0 = *(const short8*)(h16 + (long)n * DFEAT + q8 * 16);
            short8 hv1 = *(const short8*)(h16 + (long)n * DFEAT + q8 * 16 + 8);
            *(short8*)&xlds[i][((2 * q8)     ^ (i & 7)) * 8] = hv0;
            *(short8*)&xlds[i][((2 * q8 + 1) ^ (i & 7)) * 8] = hv1;

            float acc[16];
            #pragma unroll
            for (int d = 0; d < 16; ++d) acc[d] = 0.f;

            #pragma unroll
            for (int k = 0; k < 16; ++k) {
                const int   ik = __shfl(k < 8 ? id0 : id1, gb2 + (k & 7), 64);
                const float wk = __shfl(k < 8 ? w0  : w1,  gb2 + (k & 7), 64);
                u32x4 nv = *(const u32x4*)(h8i + (long)ik * DFEAT + q8 * 16);
                #pragma unroll
                for (int b = 0; b < 4; ++b) {
                    const unsigned u = nv[b];
                    acc[b * 4 + 0] += wk * (float)(signed char)(u & 0xFF);
                    acc[b * 4 + 1] += wk * (float)(signed char)((u >> 8) & 0xFF);
                    acc[b * 4 + 2] += wk * (float)(signed char)((u >> 16) & 0xFF);
                    acc[b * 4 + 3] += wk * (float)(signed char)(u >> 24);
                }
            }

            short8 ab0, ab1;
            #pragma unroll
            for (int d = 0; d < 8; ++d) { ab0[d] = f2bf(acc[d]); ab1[d] = f2bf(acc[8 + d]); }
            *(short8*)&xlds[i][((16 + 2 * q8)     ^ (i & 7)) * 8] = ab0;
            *(short8*)&xlds[i][((16 + 2 * q8 + 1) ^ (i & 7)) * 8] = ab1;
        }
    } else if constexpr (MODE == 1) {
        const int q  = l & 15;
        const int gb = l & 48;
        const int i0 = wvi * 16 + (l >> 4) * 4;
        #pragma unroll 1
        for (int r = 0; r < 4; ++r) {
            const int i = i0 + r;
            int n = nb + i; if (n >= N) n = N - 1;
            const int e0 = n * KNBR + q;
            int myidx = nbr32[idx64 ? 2 * e0 : e0];
            float myw = nbrw[e0];
            short8 hv = *(const short8*)(h16 + (long)n * DFEAT + q * 8);
            float acc[8] = {0.f,0.f,0.f,0.f,0.f,0.f,0.f,0.f};
            #pragma unroll
            for (int k = 0; k < KNBR; ++k) {
                int ik = __shfl(myidx, gb + k, 64);
                short8 nv = *(const short8*)(h16 + (long)ik * DFEAT + q * 8);
                float wk = __shfl(myw, gb + k, 64);
                #pragma unroll
                for (int d = 0; d < 8; ++d)
                    acc[d] += wk * bf2f((unsigned short)nv[d]);
            }
            *(short8*)&xlds[i][(q ^ (i & 7)) * 8] = hv;
            short8 ab;
            #pragma unroll
            for (int d = 0; d < 8; ++d) ab[d] = f2bf(acc[d]);
            *(short8*)&xlds[i][((16 + q) ^ (i & 7)) * 8] = ab;
        }
    } else {
        const int q  = l & 15;
        const int i0 = wvi * 16 + (l >> 4) * 4;
        #pragma unroll 1
        for (int r = 0; r < 4; ++r) {
            const int i = i0 + r;
            int n = nb + i; if (n >= N) n = N - 1;
            short8 hv;
            float acc[8] = {0.f,0.f,0.f,0.f,0.f,0.f,0.f,0.f};
            const f32x4* hrow = (const f32x4*)(h + (long)n * DFEAT + q * 8);
            f32x4 h0 = hrow[0], h1 = hrow[1];
            hv[0] = f2bf(h0[0]); hv[1] = f2bf(h0[1]); hv[2] = f2bf(h0[2]); hv[3] = f2bf(h0[3]);
            hv[4] = f2bf(h1[0]); hv[5] = f2bf(h1[1]); hv[6] = f2bf(h1[2]); hv[7] = f2bf(h1[3]);
            const int e0 = n * KNBR;
            #pragma unroll 4
            for (int k = 0; k < KNBR; ++k) {
                float w = nbrw[e0 + k];
                int idx = nbr32[idx64 ? 2 * (e0 + k) : (e0 + k)];
                const f32x4* nrow = (const f32x4*)(h + (long)idx * DFEAT + q * 8);
                f32x4 n0 = nrow[0], n1 = nrow[1];
                acc[0] += w * n0[0]; acc[1] += w * n0[1];
                acc[2] += w * n0[2]; acc[3] += w * n0[3];
                acc[4] += w * n1[0]; acc[5] += w * n1[1];
                acc[6] += w * n1[2]; acc[7] += w * n1[3];
            }
            *(short8*)&xlds[i][(q ^ (i & 7)) * 8] = hv;
            short8 ab;
            #pragma unroll
            for (int d = 0; d < 8; ++d) ab[d] = f2bf(acc[d]);
            *(short8*)&xlds[i][((16 + q) ^ (i & 7)) * 8] = ab;
        }
    }
    __syncthreads();

    // ---------------- Phase 2: MFMA GEMM (64 nodes x 128 j, K=256) ----------------
    const int wv  = wvi;          // wave owns j in [wv*32, wv*32+32)
    const int col = l & 15;
    const int kg  = l >> 4;       // 0..3

    f32x4 acc2[4][2];
    #pragma unroll
    for (int s = 0; s < 4; ++s)
        #pragma unroll
        for (int t = 0; t < 2; ++t)
            acc2[s][t] = (f32x4){0.f, 0.f, 0.f, 0.f};

    const unsigned short* wbase0 = wcat + (wv * 32 + col) * 256 + kg * 8;
    const unsigned short* wbase1 = wbase0 + 16 * 256;

    #pragma unroll
    for (int kk = 0; kk < 8; ++kk) {
        short8 b0 = *(const short8*)(wbase0 + kk * 32);   // B[k][col] = Wcat[j][k]
        short8 b1 = *(const short8*)(wbase1 + kk * 32);
        #pragma unroll
        for (int s = 0; s < 4; ++s) {
            const int row = s * 16 + col;                  // A row = node in tile
            const int c = (kk * 4 + kg) ^ (row & 7);       // swizzled 16B chunk
            short8 a = *(const short8*)&xlds[row][c * 8];
            acc2[s][0] = __builtin_amdgcn_mfma_f32_16x16x32_bf16(a, b0, acc2[s][0], 0, 0, 0);
            acc2[s][1] = __builtin_amdgcn_mfma_f32_16x16x32_bf16(a, b1, acc2[s][1], 0, 0, 0);
        }
    }

    // ---------------- Phase 3: GELU (exact erf) ----------------
    float y[4][2][4];
    #pragma unroll
    for (int s = 0; s < 4; ++s)
        #pragma unroll
        for (int t = 0; t < 2; ++t)
            #pragma unroll
            for (int r = 0; r < 4; ++r) {
                float x = acc2[s][t][r];
                y[s][t][r] = 0.5f * x * (1.0f + erff(x * 0.70710678118654752f));
            }

    __syncthreads();   // all xlds reads done before LN-scratch overlay writes

    // overlay LN scratch on the dead x tile
    float* lsum = (float*)&xlds[0][0];        // [4][64]
    float* lsq  = lsum + 4 * NPB;             // [4][64]

    // ---------------- Phase 4: LN stats ----------------
    #pragma unroll
    for (int s = 0; s < 4; ++s) {
        f32x4 sm, sq;
        #pragma unroll
        for (int r = 0; r < 4; ++r) {
            float a0 = y[s][0][r], a1 = y[s][1][r];
            sm[r] = a0 + a1;
            sq[r] = a0 * a0 + a1 * a1;
        }
        #pragma unroll
        for (int m = 1; m < 16; m <<= 1) {
            #pragma unroll
            for (int r = 0; r < 4; ++r) {
                sm[r] += __shfl_xor(sm[r], m, 64);
                sq[r] += __shfl_xor(sq[r], m, 64);
            }
        }
        if (col == 0) {
            *(f32x4*)&lsum[wv * NPB + s * 16 + kg * 4] = sm;
            *(f32x4*)&lsq [wv * NPB + s * 16 + kg * 4] = sq;
        }
    }
    __syncthreads();

    // ---------------- Phase 5: LN apply + store (non-temporal) ----------------
    const float g0  = gamma[wv * 32 + col];
    const float g1  = gamma[wv * 32 + 16 + col];
    const float be0 = beta [wv * 32 + col];
    const float be1 = beta [wv * 32 + 16 + col];

    #pragma unroll
    for (int s = 0; s < 4; ++s) {
        f32x4 sm = {0.f,0.f,0.f,0.f}, sq = {0.f,0.f,0.f,0.f};
        #pragma unroll
        for (int u = 0; u < 4; ++u) {
            f32x4 a = *(const f32x4*)&lsum[u * NPB + s * 16 + kg * 4];
            f32x4 b = *(const f32x4*)&lsq [u * NPB + s * 16 + kg * 4];
            sm += a; sq += b;
        }
        #pragma unroll
        for (int r = 0; r < 4; ++r) {
            const int i = s * 16 + kg * 4 + r;
            const int n = nb + i;
            if (n < N) {
                float mean = sm[r] * (1.0f / 128.0f);
                float var  = sq[r] * (1.0f / 128.0f) - mean * mean;
                float rstd = rsqrtf(var + 1e-5f);
                long o = (long)n * DFEAT + wv * 32 + col;
                __builtin_nontemporal_store((y[s][0][r] - mean) * rstd * g0 + be0, &out[o]);
                __builtin_nontemporal_store((y[s][1][r] - mean) * rstd * g1 + be1, &out[o + 16]);
            }
        }
    }
}

extern "C" void kernel_launch(void* const* d_in, const int* in_sizes, int n_in,
                              void* d_out, int out_size, void* d_ws, size_t ws_size,
                              hipStream_t stream) {
    const float* h     = (const float*)d_in[0];
    const int*   nbr   = (const int*)  d_in[1];
    const float* nbrw  = (const float*)d_in[2];
    const float* wself = (const float*)d_in[3];
    const float* wnei  = (const float*)d_in[4];
    const float* gamma = (const float*)d_in[5];
    const float* beta  = (const float*)d_in[6];
    const int N = in_sizes[0] / DFEAT;

    // layout: wcat 64K | h16 N*256 | sc N*4 | h8i N*128
    unsigned short* wcat = (unsigned short*)d_ws;
    unsigned short* h16  = (unsigned short*)((char*)d_ws + 65536);
    float*          sc   = (float*)((char*)d_ws + 65536 + (size_t)N * DFEAT * 2);
    unsigned char*  h8i  = (unsigned char*)((char*)sc + (size_t)N * 4);
    const size_t need16 = 65536 + (size_t)N * DFEAT * 2;
    const size_t need3  = need16 + (size_t)N * 4 + (size_t)N * DFEAT;

    const int blocks = (N + NPB - 1) / NPB;
    const int ntot8 = N * DFEAT / 8;
    const int pthreads = 4096 + ntot8;

    if (ws_size >= need3) {
        prep_kernel<<<(pthreads + 255) / 256, 256, 0, stream>>>(h, wself, wnei, h16, wcat, h8i, sc, ntot8);
        sage_fused_kernel<3><<<blocks, 256, 0, stream>>>(h, h16, h8i, sc, nbr, nbrw, wcat,
                                                         gamma, beta, (float*)d_out, N);
    } else if (ws_size >= need16) {
        prep_kernel<<<(pthreads + 255) / 256, 256, 0, stream>>>(h, wself, wnei, h16, wcat,
                                                                (unsigned char*)nullptr, (float*)nullptr, ntot8);
        sage_fused_kernel<1><<<blocks, 256, 0, stream>>>(h, h16, (const unsigned char*)nullptr,
                                                         (const float*)nullptr, nbr, nbrw, wcat,
                                                         gamma, beta, (float*)d_out, N);
    } else {
        prep_kernel<<<(4096 + 255) / 256, 256, 0, stream>>>(h, wself, wnei, h16, wcat,
                                                            (unsigned char*)nullptr, (float*)nullptr, 0);
        sage_fused_kernel<0><<<blocks, 256, 0, stream>>>(h, (const unsigned short*)nullptr,
                                                         (const unsigned char*)nullptr,
                                                         (const float*)nullptr, nbr, nbrw, wcat,
                                                         gamma, beta, (float*)d_out, N);
    }
}